// Round 4
// baseline (172.037 us; speedup 1.0000x reference)
//
#include <hip/hip_runtime.h>

#define B_TOT 65536
#define R 12
#define L 16
#define NB 8
#define NEG_MIN -3.402823466e38f

// ws layout (float index):
//   [0,32)   v[j]  (kw2 . qb2)
//   [32]     c     (qb2 . kb2)
//   [40,52)  pmask (as int: bit l set if freq_mask[r][l] != 0)
//   [64,96)  sorted breakpoints t[32]
//   [96, 96+33*72) interval table: row m (72 floats, 288 B)
//   [2472, 2472+1024) L1 weight MFMA fragments as shorts:
//        frag fr (=term*2+tile) : 64 lanes x short8; lane=kb*16+jl holds
//        Wterm[q(tile,jl)][kb*8..+7], q = (jl>>2)*8 + tile*4 + (jl&3)
#define WS_V   0
#define WS_C   32
#define WS_PM  40
#define WS_BP  64
#define WS_TAB 96
#define TROW   72
#define WS_WF  2472

// per-wave s_in region: 4 batches x 16 rows x 40 shorts + 8 pad shorts
#define WROWS (4 * 16 * 40 + 8)

typedef __attribute__((ext_vector_type(8))) short short8;
typedef __attribute__((ext_vector_type(4))) float f32x4;

static __device__ __forceinline__ short f2bf(float f) {
    uint32_t u = __float_as_uint(f);
    uint32_t r = u + 0x7FFFu + ((u >> 16) & 1u);  // round-to-nearest-even
    return (short)(r >> 16);
}

// HW packed f32->bf16 (RNE), 1 instruction for 2 elements.
static __device__ __forceinline__ unsigned cvt_pk_bf16(float a, float b) {
    unsigned d;
    asm("v_cvt_pk_bf16_f32 %0, %1, %2" : "=v"(d) : "v"(a), "v"(b));
    return d;
}

__global__ __launch_bounds__(256) void nfh_pre(
    const float* __restrict__ qw1, const float* __restrict__ qb1,
    const float* __restrict__ qw2, const float* __restrict__ qb2,
    const float* __restrict__ kw2, const float* __restrict__ kb2,
    const float* __restrict__ kw1, const float* __restrict__ kb1,
    const int*   __restrict__ fmask,
    float* __restrict__ ws)
{
    __shared__ float sM[1024];
    __shared__ float su[32];
    __shared__ float sw1[32], sb1[32], sbp[32], sbq[32];
    const int t = threadIdx.x;

    if (t < 32) { sw1[t] = qw1[t]; sb1[t] = qb1[t]; }
    for (int e = t; e < 1024; e += 256) {
        const int i = e >> 5, j = e & 31;
        float acc = 0.f;
        for (int h = 0; h < 64; ++h) acc = fmaf(qw2[i * 64 + h], kw2[j * 64 + h], acc);
        sM[e] = acc;
    }
    if (t < 32) {
        float au = 0.f, av = 0.f;
        for (int h = 0; h < 64; ++h) {
            au = fmaf(qw2[t * 64 + h], kb2[h], au);
            av = fmaf(kw2[t * 64 + h], qb2[h], av);
        }
        su[t] = au;
        ws[WS_V + t] = av;
        const float w = qw1[t];
        sbp[t] = (w != 0.f) ? (-qb1[t] / w) : 3.0e30f;
    }
    if (t == 64) {
        float acc = 0.f;
        for (int h = 0; h < 64; ++h) acc = fmaf(qb2[h], kb2[h], acc);
        ws[WS_C] = acc;
    }
    if (t < 12) {
        int pm = 0;
        for (int l = 0; l < 16; ++l) if (fmask[t * 16 + l] != 0) pm |= (1 << l);
        ((int*)ws)[WS_PM + t] = pm;
    }
    __syncthreads();
    // Parallel stable rank-sort of the 32 breakpoints (bit-identical to a
    // stable insertion sort on this NaN-free array).
    if (t < 32) {
        const float key = sbp[t];
        int rank = 0;
        #pragma unroll
        for (int i = 0; i < 32; ++i) {
            const float vi = sbp[i];
            rank += (vi < key || (vi == key && i < t)) ? 1 : 0;
        }
        sbq[rank] = key;
    }
    __syncthreads();
    if (t < 32) ws[WS_BP + t] = sbq[t];

    for (int task = t; task < 33 * 32 + 33; task += 256) {
        const int m = (task < 33 * 32) ? (task >> 5) : (task - 33 * 32);
        const float xi = (m == 0) ? sbq[0] - 1.f
                       : ((m == 32) ? sbq[31] + 1.f
                                    : sbq[m - 1] + 0.5f * (sbq[m] - sbq[m - 1]));
        if (task < 33 * 32) {
            const int j = task & 31;
            float A = 0.f, Bv = 0.f;
            for (int i = 0; i < 32; ++i) {
                if (fmaf(sw1[i], xi, sb1[i]) > 0.f) {
                    A  = fmaf(sw1[i], sM[i * 32 + j], A);
                    Bv = fmaf(sb1[i], sM[i * 32 + j], Bv);
                }
            }
            ws[WS_TAB + m * TROW + j] = A;
            ws[WS_TAB + m * TROW + 36 + j] = Bv;
        } else {
            float Au = 0.f, Bu = 0.f;
            for (int i = 0; i < 32; ++i) {
                if (fmaf(sw1[i], xi, sb1[i]) > 0.f) {
                    Au = fmaf(sw1[i], su[i], Au);
                    Bu = fmaf(sb1[i], su[i], Bu);
                }
            }
            ws[WS_TAB + m * TROW + 32] = Au;
            ws[WS_TAB + m * TROW + 36 + 32] = Bu;
        }
    }

    // ---- L1 weight MFMA fragments (hi/lo split), 4 frags x 64 lanes ----
    {
        const int fr = t >> 6;            // 0:t1T0 1:t1T1 2:t2T0 3:t2T1
        const int li = t & 63;
        const int jl = li & 15, kb = li >> 4;
        const int T = fr & 1, term = fr >> 1;
        const int q = ((jl >> 2) << 3) + (T << 2) + (jl & 3);
        short* wsp = (short*)(ws + WS_WF);
        #pragma unroll
        for (int e = 0; e < 8; ++e) {
            const int k = kb * 8 + e;
            float w = 0.f;
            if (term == 0) {
                if (k < 11)       w = kw1[k * 32 + q];
                else if (k == 11) w = kb1[q];
            } else {
                if (k < 11)       w = kw1[k * 32 + q];            // wh (for lo*wh)
                else if (k == 11) { const float b = kb1[q];
                                    w = b - __uint_as_float(((uint32_t)(uint16_t)f2bf(b)) << 16); }
                else if (k < 23)  { const float a = kw1[(k - 12) * 32 + q];
                                    w = a - __uint_as_float(((uint32_t)(uint16_t)f2bf(a)) << 16); }
            }
            wsp[(fr * 64 + li) * 8 + e] = f2bf(w);
        }
    }
}

// Barrier-free main: 128 threads = 2 waves; wave w is fully self-contained
// for batches w*4..w*4+3 (P1/P2a producers and P3 consumers are the same
// wave), so cross-wave __syncthreads is replaced by one s_waitcnt lgkmcnt(0).
__global__ __launch_bounds__(128, 4) void nfh_main(
    const float* __restrict__ rss,   // [B,R]
    const float* __restrict__ feat,  // [B,L,F]
    const float* __restrict__ pos,   // [B,L,3]
    const float* __restrict__ prev,  // [B,3]
    const float* __restrict__ gw1, const float* __restrict__ gb1,
    const float* __restrict__ gw2, const float* __restrict__ gb2,
    const float* __restrict__ sigma_p,
    const float* __restrict__ ws,
    float* __restrict__ out)
{
    // s_in: per-wave region of 4x16 rows x 40 shorts (+8 pad shorts so the
    // last row's overlapped i2 read stays inside this wave's region):
    //   [0,16)  term1 K-slots: hi(in0..10), 1.0, 0,0,0,0
    //   [16,40) term2 K-slots: lo(in0..10), 1.0lo, hi(in0..10), 0
    __shared__ short s_in[2 * WROWS];   // 10,272 B
    __shared__ short s_ttf[NB * 384];   // 6,144 B
    __shared__ float s_dq[NB * 16];     // 512 B: c - dsq/(2s^2) per (bb,l)
    __shared__ float s_tc[NB * 12];     // 384 B

    const int t = threadIdx.x;
    const int lane = t & 63;
    const int wv = t >> 6;
    const int lg = lane >> 4;
    const int b0 = blockIdx.x * NB;
    const float sigma = sigma_p[0];
    const float inv2s2 = 1.f / (2.f * sigma * sigma);

    // L1 weight frags + v-frag + c (uniform across blocks -> L2 broadcast)
    const short* wsp = (const short*)(ws + WS_WF);
    const short8 wf0 = *(const short8*)(wsp + (0 * 64 + lane) * 8);
    const short8 wf1 = *(const short8*)(wsp + (1 * 64 + lane) * 8);
    const short8 wf2 = *(const short8*)(wsp + (2 * 64 + lane) * 8);
    const short8 wf3 = *(const short8*)(wsp + (3 * 64 + lane) * 8);
    const f32x4 v0 = *(const f32x4*)(ws + WS_V + lg * 8);
    const f32x4 v1 = *(const f32x4*)(ws + WS_V + lg * 8 + 4);
    const float cconst = ws[WS_C];

    // per-wave pad zero (consumed only x0-weight, but keep bits finite)
    if (lane < 8) s_in[wv * WROWS + 4 * 16 * 40 + lane] = 0;

    // ---------- P1: (bb1 = t>>4, l1 = t&15): load, hi/lo split -> LDS rows ----------
    {
        const int bb1 = t >> 4, l1 = t & 15;
        const int b = b0 + bb1;
        float in[12];
        const float4* f4 = (const float4*)(feat + ((size_t)b * (L * 8) + l1 * 8));
        const float4 fa = f4[0], fb = f4[1];
        in[0] = fa.x; in[1] = fa.y; in[2] = fa.z; in[3] = fa.w;
        in[4] = fb.x; in[5] = fb.y; in[6] = fb.z; in[7] = fb.w;
        const float* pp = pos + ((size_t)b * (L * 3) + l1 * 3);
        in[8] = pp[0]; in[9] = pp[1]; in[10] = pp[2];
        in[11] = 1.0f;

        float dsq = 0.f;
        #pragma unroll
        for (int m = 0; m < 3; ++m) {
            const float d = prev[b * 3 + m] - in[8 + m];
            dsq = fmaf(d, d, dsq);
        }
        s_dq[bb1 * 16 + l1] = cconst - dsq * inv2s2;

        unsigned hp[6], lp[6];
        #pragma unroll
        for (int p = 0; p < 6; ++p) {
            const float a = in[2 * p], c = in[2 * p + 1];
            const unsigned h = cvt_pk_bf16(a, c);
            hp[p] = h;
            const float h0 = __uint_as_float(h << 16);
            const float h1 = __uint_as_float(h & 0xFFFF0000u);
            lp[p] = cvt_pk_bf16(a - h0, c - h1);
        }
        const unsigned lp5m = (lp[5] & 0xFFFFu) | 0x3F800000u;  // slot11 = 1.0 (bias-lo)

        uint4* rowp = (uint4*)&s_in[wv * WROWS + ((bb1 & 3) * 16 + l1) * 40];
        rowp[0] = make_uint4(hp[0], hp[1], hp[2], hp[3]);
        rowp[1] = make_uint4(hp[4], hp[5], 0u, 0u);
        rowp[2] = make_uint4(lp[0], lp[1], lp[2], lp[3]);
        rowp[3] = make_uint4(lp[4], lp5m, hp[0], hp[1]);
        rowp[4] = make_uint4(hp[2], hp[3], hp[4], hp[5] & 0xFFFFu);
    }

    // ---------- P2a: (bb2 = t>>4, r2 = t&15), active if r2 < 12 ----------
    if ((t & 15) < R) {
        const int bb2 = t >> 4;
        const int r2 = t & 15;
        const int b = b0 + bb2;
        const float x = rss[(size_t)b * R + r2];
        float z = gb2[0];
        #pragma unroll
        for (int i = 0; i < 16; ++i) {
            const float h = fmaxf(fmaf(x, gw1[i], gb1[i]), 0.f);
            z = fmaf(h, gw2[i], z);
        }
        const float gate = 1.f / (1.f + __expf(-z));
        const float iw = (x > 0.5f) ? gate : 0.f;
        out[(size_t)B_TOT * R * L + (size_t)b * R + r2] = iw;
        const float xq = x * iw;

        int k = 0;
        #pragma unroll
        for (int m = 0; m < 32; ++m) k += (xq > ws[WS_BP + m]) ? 1 : 0;
        const float* row = ws + WS_TAB + k * TROW;
        const float4* ra = (const float4*)row;
        const float4* rb = (const float4*)(row + 36);
        s_tc[bb2 * 12 + r2] = fmaf(xq, row[32], row[68]);
        #pragma unroll
        for (int kb = 0; kb < 4; ++kb) {
            const float4 a0 = ra[kb * 2], c0 = rb[kb * 2];
            const float4 a1 = ra[kb * 2 + 1], c1 = rb[kb * 2 + 1];
            uint4 pk;
            pk.x = cvt_pk_bf16(fmaf(xq, a0.x, c0.x), fmaf(xq, a0.y, c0.y));
            pk.y = cvt_pk_bf16(fmaf(xq, a0.z, c0.z), fmaf(xq, a0.w, c0.w));
            pk.z = cvt_pk_bf16(fmaf(xq, a1.x, c1.x), fmaf(xq, a1.y, c1.y));
            pk.w = cvt_pk_bf16(fmaf(xq, a1.z, c1.z), fmaf(xq, a1.w, c1.w));
            *(uint4*)&s_ttf[bb2 * 384 + (kb * 12 + r2) * 8] = pk;
        }
    }

    // Intra-wave LDS visibility: all of this wave's ds_writes complete.
    asm volatile("s_waitcnt lgkmcnt(0)" ::: "memory");

    // ---------- P3: wave wv, batches wv*4..wv*4+3 ----------
    {
        const int r = lane & 15;
        const int pm = (r < R) ? ((const int*)ws)[WS_PM + r] : 0;

        #pragma unroll
        for (int i = 0; i < 4; ++i) {
            const int bb = wv * 4 + i;
            const short* rowb = &s_in[wv * WROWS + (i * 16 + r) * 40];
            const short8 i1 = *(const short8*)(rowb + lg * 8);
            const short8 i2 = *(const short8*)(rowb + 16 + lg * 8);

            f32x4 d0 = {0.f, 0.f, 0.f, 0.f};
            f32x4 d1 = {0.f, 0.f, 0.f, 0.f};
            d0 = __builtin_amdgcn_mfma_f32_16x16x32_bf16(wf0, i1, d0, 0, 0, 0);
            d0 = __builtin_amdgcn_mfma_f32_16x16x32_bf16(wf2, i2, d0, 0, 0, 0);
            d1 = __builtin_amdgcn_mfma_f32_16x16x32_bf16(wf1, i1, d1, 0, 0, 0);
            d1 = __builtin_amdgcn_mfma_f32_16x16x32_bf16(wf3, i2, d1, 0, 0, 0);

            float vbp = 0.f;
            #pragma unroll
            for (int j = 0; j < 4; ++j) {
                d0[j] = fmaxf(d0[j], 0.f);
                vbp = fmaf(v0[j], d0[j], vbp);
            }
            #pragma unroll
            for (int j = 0; j < 4; ++j) {
                d1[j] = fmaxf(d1[j], 0.f);
                vbp = fmaf(v1[j], d1[j], vbp);
            }
            vbp += __shfl_xor(vbp, 16);
            vbp += __shfl_xor(vbp, 32);
            const float vbl = vbp + s_dq[bb * 16 + r];  // valid at every lane for l=lane&15

            uint4 afp;
            afp.x = cvt_pk_bf16(d0[0], d0[1]);
            afp.y = cvt_pk_bf16(d0[2], d0[3]);
            afp.z = cvt_pk_bf16(d1[0], d1[1]);
            afp.w = cvt_pk_bf16(d1[2], d1[3]);
            const short8 af = *(const short8*)&afp;

            short8 bf = (short8){0, 0, 0, 0, 0, 0, 0, 0};
            float tc = 0.f;
            if (r < R) {
                bf = *(const short8*)&s_ttf[bb * 384 + (lg * 12 + r) * 8];
                tc = s_tc[bb * 12 + r];
            }
            f32x4 acc = {0.f, 0.f, 0.f, 0.f};
            acc = __builtin_amdgcn_mfma_f32_16x16x32_bf16(af, bf, acc, 0, 0, 0);

            float sc[4];
            #pragma unroll
            for (int j = 0; j < 4; ++j) {
                const float vbj = __shfl(vbl, lg * 4 + j);
                sc[j] = acc[j] + tc + vbj;
                if (!((pm >> (lg * 4 + j)) & 1)) sc[j] = NEG_MIN;
            }
            float mx = fmaxf(fmaxf(sc[0], sc[1]), fmaxf(sc[2], sc[3]));
            mx = fmaxf(mx, __shfl_xor(mx, 16));
            mx = fmaxf(mx, __shfl_xor(mx, 32));
            float sum = 0.f;
            #pragma unroll
            for (int j = 0; j < 4; ++j) { sc[j] = __expf(sc[j] - mx); sum += sc[j]; }
            sum += __shfl_xor(sum, 16);
            sum += __shfl_xor(sum, 32);
            const float inv = 1.f / sum;

            if (r < R) {
                float4* op = (float4*)(out + ((size_t)(b0 + bb) * R + r) * L + lg * 4);
                *op = make_float4(sc[0] * inv, sc[1] * inv, sc[2] * inv, sc[3] * inv);
            }
        }
    }
}

extern "C" void kernel_launch(void* const* d_in, const int* in_sizes, int n_in,
                              void* d_out, int out_size, void* d_ws, size_t ws_size,
                              hipStream_t stream) {
    const float* rss   = (const float*)d_in[0];
    const float* feat  = (const float*)d_in[1];
    const float* pos   = (const float*)d_in[2];
    const float* prev  = (const float*)d_in[3];
    const int*   fmask = (const int*)d_in[4];
    const float* gw1   = (const float*)d_in[5];
    const float* gb1   = (const float*)d_in[6];
    const float* gw2   = (const float*)d_in[7];
    const float* gb2   = (const float*)d_in[8];
    const float* qw1   = (const float*)d_in[9];
    const float* qb1   = (const float*)d_in[10];
    const float* qw2   = (const float*)d_in[11];
    const float* qb2   = (const float*)d_in[12];
    const float* kw1   = (const float*)d_in[13];
    const float* kb1   = (const float*)d_in[14];
    const float* kw2   = (const float*)d_in[15];
    const float* kb2   = (const float*)d_in[16];
    const float* sigma = (const float*)d_in[17];
    float* out = (float*)d_out;
    float* ws  = (float*)d_ws;

    nfh_pre<<<1, 256, 0, stream>>>(qw1, qb1, qw2, qb2, kw2, kb2, kw1, kb1, fmask, ws);
    nfh_main<<<B_TOT / NB, 128, 0, stream>>>(
        rss, feat, pos, prev,
        gw1, gb1, gw2, gb2,
        sigma, ws, out);
}

// Round 5
// 162.297 us; speedup vs baseline: 1.0600x; 1.0600x over previous
//
#include <hip/hip_runtime.h>

#define B_TOT 65536
#define R 12
#define L 16
#define NB 16
#define NEG_MIN -3.402823466e38f

// ws layout (float index):
//   [0,32)   v[j]  (kw2 . qb2)
//   [32]     c     (qb2 . kb2)
//   [40,52)  pmask (as int: bit l set if freq_mask[r][l] != 0)
//   [64,96)  sorted breakpoints t[32]
//   [96, 96+33*72) interval table: row m (72 floats, 288 B)
//   [2472, 2472+1024) L1 weight MFMA fragments as shorts:
//        frag fr (=term*2+tile) : 64 lanes x short8; lane=kb*16+jl holds
//        Wterm[q(tile,jl)][kb*8..+7], q = (jl>>2)*8 + tile*4 + (jl&3)
#define WS_V   0
#define WS_C   32
#define WS_PM  40
#define WS_BP  64
#define WS_TAB 96
#define TROW   72
#define WS_WF  2472

// per-wave s_in region: 4 batches x 16 rows x 40 shorts + 8 pad shorts
#define WROWS (4 * 16 * 40 + 8)

typedef __attribute__((ext_vector_type(8))) short short8;
typedef __attribute__((ext_vector_type(4))) float f32x4;

static __device__ __forceinline__ short f2bf(float f) {
    uint32_t u = __float_as_uint(f);
    uint32_t r = u + 0x7FFFu + ((u >> 16) & 1u);  // round-to-nearest-even
    return (short)(r >> 16);
}

// HW packed f32->bf16 (RNE), 1 instruction for 2 elements.
static __device__ __forceinline__ unsigned cvt_pk_bf16(float a, float b) {
    unsigned d;
    asm("v_cvt_pk_bf16_f32 %0, %1, %2" : "=v"(d) : "v"(a), "v"(b));
    return d;
}

__global__ __launch_bounds__(256) void nfh_pre(
    const float* __restrict__ qw1, const float* __restrict__ qb1,
    const float* __restrict__ qw2, const float* __restrict__ qb2,
    const float* __restrict__ kw2, const float* __restrict__ kb2,
    const float* __restrict__ kw1, const float* __restrict__ kb1,
    const int*   __restrict__ fmask,
    float* __restrict__ ws)
{
    __shared__ float sM[1024];
    __shared__ float su[32];
    __shared__ float sw1[32], sb1[32], sbp[32], sbq[32];
    const int t = threadIdx.x;

    if (t < 32) { sw1[t] = qw1[t]; sb1[t] = qb1[t]; }
    for (int e = t; e < 1024; e += 256) {
        const int i = e >> 5, j = e & 31;
        float acc = 0.f;
        for (int h = 0; h < 64; ++h) acc = fmaf(qw2[i * 64 + h], kw2[j * 64 + h], acc);
        sM[e] = acc;
    }
    if (t < 32) {
        float au = 0.f, av = 0.f;
        for (int h = 0; h < 64; ++h) {
            au = fmaf(qw2[t * 64 + h], kb2[h], au);
            av = fmaf(kw2[t * 64 + h], qb2[h], av);
        }
        su[t] = au;
        ws[WS_V + t] = av;
        const float w = qw1[t];
        sbp[t] = (w != 0.f) ? (-qb1[t] / w) : 3.0e30f;
    }
    if (t == 64) {
        float acc = 0.f;
        for (int h = 0; h < 64; ++h) acc = fmaf(qb2[h], kb2[h], acc);
        ws[WS_C] = acc;
    }
    if (t < 12) {
        int pm = 0;
        for (int l = 0; l < 16; ++l) if (fmask[t * 16 + l] != 0) pm |= (1 << l);
        ((int*)ws)[WS_PM + t] = pm;
    }
    __syncthreads();
    // Parallel stable rank-sort of the 32 breakpoints (bit-identical to a
    // stable insertion sort on this NaN-free array).
    if (t < 32) {
        const float key = sbp[t];
        int rank = 0;
        #pragma unroll
        for (int i = 0; i < 32; ++i) {
            const float vi = sbp[i];
            rank += (vi < key || (vi == key && i < t)) ? 1 : 0;
        }
        sbq[rank] = key;
    }
    __syncthreads();
    if (t < 32) ws[WS_BP + t] = sbq[t];

    for (int task = t; task < 33 * 32 + 33; task += 256) {
        const int m = (task < 33 * 32) ? (task >> 5) : (task - 33 * 32);
        const float xi = (m == 0) ? sbq[0] - 1.f
                       : ((m == 32) ? sbq[31] + 1.f
                                    : sbq[m - 1] + 0.5f * (sbq[m] - sbq[m - 1]));
        if (task < 33 * 32) {
            const int j = task & 31;
            float A = 0.f, Bv = 0.f;
            for (int i = 0; i < 32; ++i) {
                if (fmaf(sw1[i], xi, sb1[i]) > 0.f) {
                    A  = fmaf(sw1[i], sM[i * 32 + j], A);
                    Bv = fmaf(sb1[i], sM[i * 32 + j], Bv);
                }
            }
            ws[WS_TAB + m * TROW + j] = A;
            ws[WS_TAB + m * TROW + 36 + j] = Bv;
        } else {
            float Au = 0.f, Bu = 0.f;
            for (int i = 0; i < 32; ++i) {
                if (fmaf(sw1[i], xi, sb1[i]) > 0.f) {
                    Au = fmaf(sw1[i], su[i], Au);
                    Bu = fmaf(sb1[i], su[i], Bu);
                }
            }
            ws[WS_TAB + m * TROW + 32] = Au;
            ws[WS_TAB + m * TROW + 36 + 32] = Bu;
        }
    }

    // ---- L1 weight MFMA fragments (hi/lo split), 4 frags x 64 lanes ----
    {
        const int fr = t >> 6;            // 0:t1T0 1:t1T1 2:t2T0 3:t2T1
        const int li = t & 63;
        const int jl = li & 15, kb = li >> 4;
        const int T = fr & 1, term = fr >> 1;
        const int q = ((jl >> 2) << 3) + (T << 2) + (jl & 3);
        short* wsp = (short*)(ws + WS_WF);
        #pragma unroll
        for (int e = 0; e < 8; ++e) {
            const int k = kb * 8 + e;
            float w = 0.f;
            if (term == 0) {
                if (k < 11)       w = kw1[k * 32 + q];
                else if (k == 11) w = kb1[q];
            } else {
                if (k < 11)       w = kw1[k * 32 + q];            // wh (for lo*wh)
                else if (k == 11) { const float b = kb1[q];
                                    w = b - __uint_as_float(((uint32_t)(uint16_t)f2bf(b)) << 16); }
                else if (k < 23)  { const float a = kw1[(k - 12) * 32 + q];
                                    w = a - __uint_as_float(((uint32_t)(uint16_t)f2bf(a)) << 16); }
            }
            wsp[(fr * 64 + li) * 8 + e] = f2bf(w);
        }
    }
}

// 256-thread, barrier-free, LDS = s_in only (~20.5 KB -> 7 blocks/CU).
// All producer->consumer flows for wave w's batches are intra-wave:
//   P1 (bb=t>>4, l=t&15) -> s_in rows (per-wave padded region)
//   P2a (bb=t>>4, r=t&15) -> xq/k/tc kept in REGISTERS, shfl'd in P3
//   P3 wave w, batches w*4..w*4+3: B-frag rebuilt in-register from the
//   L1-resident interval table (bit-identical fmaf/cvt_pk sequence).
__global__ __launch_bounds__(256, 8) void nfh_main(
    const float* __restrict__ rss,   // [B,R]
    const float* __restrict__ feat,  // [B,L,F]
    const float* __restrict__ pos,   // [B,L,3]
    const float* __restrict__ prev,  // [B,3]
    const float* __restrict__ gw1, const float* __restrict__ gb1,
    const float* __restrict__ gw2, const float* __restrict__ gb2,
    const float* __restrict__ sigma_p,
    const float* __restrict__ ws,
    float* __restrict__ out)
{
    // s_in: per-wave region of 4x16 rows x 40 shorts (+8 pad shorts):
    //   [0,16)  term1 K-slots: hi(in0..10), 1.0, 0,0,0,0
    //   [16,40) term2 K-slots: lo(in0..10), 1.0lo, hi(in0..10), 0
    __shared__ short s_in[4 * WROWS];   // 20,544 B

    const int t = threadIdx.x;
    const int lane = t & 63;
    const int wv = t >> 6;
    const int lg = lane >> 4;
    const int b0 = blockIdx.x * NB;
    const float sigma = sigma_p[0];
    const float inv2s2 = 1.f / (2.f * sigma * sigma);

    // L1 weight frags + v-frag + c (uniform across blocks -> L2 broadcast)
    const short* wsp = (const short*)(ws + WS_WF);
    const short8 wf0 = *(const short8*)(wsp + (0 * 64 + lane) * 8);
    const short8 wf1 = *(const short8*)(wsp + (1 * 64 + lane) * 8);
    const short8 wf2 = *(const short8*)(wsp + (2 * 64 + lane) * 8);
    const short8 wf3 = *(const short8*)(wsp + (3 * 64 + lane) * 8);
    const f32x4 v0 = *(const f32x4*)(ws + WS_V + lg * 8);
    const f32x4 v1 = *(const f32x4*)(ws + WS_V + lg * 8 + 4);
    const float cconst = ws[WS_C];

    // per-wave pad zero (read only via 0-weight K-slots; keep bits finite)
    if (lane < 8) s_in[wv * WROWS + 4 * 16 * 40 + lane] = 0;

    float my_dq;   // c - dsq/(2s^2) for (bb=t>>4, l=t&15)
    // ---------- P1: (bb1 = t>>4, l1 = t&15): load, hi/lo split -> LDS rows ----------
    {
        const int bb1 = t >> 4, l1 = t & 15;
        const int b = b0 + bb1;
        float in[12];
        const float4* f4 = (const float4*)(feat + ((size_t)b * (L * 8) + l1 * 8));
        const float4 fa = f4[0], fb = f4[1];
        in[0] = fa.x; in[1] = fa.y; in[2] = fa.z; in[3] = fa.w;
        in[4] = fb.x; in[5] = fb.y; in[6] = fb.z; in[7] = fb.w;
        const float* pp = pos + ((size_t)b * (L * 3) + l1 * 3);
        in[8] = pp[0]; in[9] = pp[1]; in[10] = pp[2];
        in[11] = 1.0f;

        float dsq = 0.f;
        #pragma unroll
        for (int m = 0; m < 3; ++m) {
            const float d = prev[b * 3 + m] - in[8 + m];
            dsq = fmaf(d, d, dsq);
        }
        my_dq = cconst - dsq * inv2s2;

        unsigned hp[6], lp[6];
        #pragma unroll
        for (int p = 0; p < 6; ++p) {
            const float a = in[2 * p], c = in[2 * p + 1];
            const unsigned h = cvt_pk_bf16(a, c);
            hp[p] = h;
            const float h0 = __uint_as_float(h << 16);
            const float h1 = __uint_as_float(h & 0xFFFF0000u);
            lp[p] = cvt_pk_bf16(a - h0, c - h1);
        }
        const unsigned lp5m = (lp[5] & 0xFFFFu) | 0x3F800000u;  // slot11 = 1.0 (bias-lo)

        uint4* rowp = (uint4*)&s_in[wv * WROWS + ((bb1 & 3) * 16 + l1) * 40];
        rowp[0] = make_uint4(hp[0], hp[1], hp[2], hp[3]);
        rowp[1] = make_uint4(hp[4], hp[5], 0u, 0u);
        rowp[2] = make_uint4(lp[0], lp[1], lp[2], lp[3]);
        rowp[3] = make_uint4(lp[4], lp5m, hp[0], hp[1]);
        rowp[4] = make_uint4(hp[2], hp[3], hp[4], hp[5] & 0xFFFFu);
    }

    // ---------- P2a: (bb2 = t>>4, r2 = t&15): gate -> iw; xq/k/tc in regs ----------
    float my_xq = 0.f;
    {
        const int bb2 = t >> 4;
        const int r2 = t & 15;
        if (r2 < R) {
            const int b = b0 + bb2;
            const float x = rss[(size_t)b * R + r2];
            float z = gb2[0];
            #pragma unroll
            for (int i = 0; i < 16; ++i) {
                const float h = fmaxf(fmaf(x, gw1[i], gb1[i]), 0.f);
                z = fmaf(h, gw2[i], z);
            }
            const float gate = 1.f / (1.f + __expf(-z));
            const float iw = (x > 0.5f) ? gate : 0.f;
            out[(size_t)B_TOT * R * L + (size_t)b * R + r2] = iw;
            my_xq = x * iw;
        }
    }
    int my_k = 0;
    #pragma unroll
    for (int m = 0; m < 32; ++m) my_k += (my_xq > ws[WS_BP + m]) ? 1 : 0;
    const float* myrow = ws + WS_TAB + my_k * TROW;
    const float my_tc = fmaf(my_xq, myrow[32], myrow[68]);

    // Intra-wave LDS visibility: this wave's ds_writes complete.
    asm volatile("s_waitcnt lgkmcnt(0)" ::: "memory");

    // ---------- P3: wave wv, batches wv*4..wv*4+3 ----------
    {
        const int r = lane & 15;
        const int pm = (r < R) ? ((const int*)ws)[WS_PM + r] : 0;
        const int j0 = lg * 8;

        #pragma unroll 1
        for (int i = 0; i < 4; ++i) {
            const int bb = wv * 4 + i;
            const int src = i * 16 + r;
            const float xq_s = __shfl(my_xq, src);
            const int   k_s  = __shfl(my_k,  src);
            const float tc_s = __shfl(my_tc, src);
            const float dq_s = __shfl(my_dq, src);

            const short* rowb = &s_in[wv * WROWS + (i * 16 + r) * 40];
            const short8 i1 = *(const short8*)(rowb + j0);
            const short8 i2 = *(const short8*)(rowb + 16 + j0);

            f32x4 d0 = {0.f, 0.f, 0.f, 0.f};
            f32x4 d1 = {0.f, 0.f, 0.f, 0.f};
            d0 = __builtin_amdgcn_mfma_f32_16x16x32_bf16(wf0, i1, d0, 0, 0, 0);
            d0 = __builtin_amdgcn_mfma_f32_16x16x32_bf16(wf2, i2, d0, 0, 0, 0);
            d1 = __builtin_amdgcn_mfma_f32_16x16x32_bf16(wf1, i1, d1, 0, 0, 0);
            d1 = __builtin_amdgcn_mfma_f32_16x16x32_bf16(wf3, i2, d1, 0, 0, 0);

            float vbp = 0.f;
            #pragma unroll
            for (int j = 0; j < 4; ++j) {
                d0[j] = fmaxf(d0[j], 0.f);
                vbp = fmaf(v0[j], d0[j], vbp);
            }
            #pragma unroll
            for (int j = 0; j < 4; ++j) {
                d1[j] = fmaxf(d1[j], 0.f);
                vbp = fmaf(v1[j], d1[j], vbp);
            }
            vbp += __shfl_xor(vbp, 16);
            vbp += __shfl_xor(vbp, 32);
            const float vbl = vbp + dq_s;  // valid at every lane for l=lane&15

            uint4 afp;
            afp.x = cvt_pk_bf16(d0[0], d0[1]);
            afp.y = cvt_pk_bf16(d0[2], d0[3]);
            afp.z = cvt_pk_bf16(d1[0], d1[1]);
            afp.w = cvt_pk_bf16(d1[2], d1[3]);
            const short8 af = *(const short8*)&afp;

            // B-frag rebuilt in-register from the interval table (L1-resident).
            // Bit-identical to the old P2a fmaf/cvt_pk sequence. Columns r>=12
            // are garbage-but-finite; they only affect discarded D columns.
            const float* rowt = ws + WS_TAB + k_s * TROW;
            const float4 a0 = *(const float4*)(rowt + j0);
            const float4 a1 = *(const float4*)(rowt + j0 + 4);
            const float4 c0 = *(const float4*)(rowt + 36 + j0);
            const float4 c1 = *(const float4*)(rowt + 36 + j0 + 4);
            uint4 bfp;
            bfp.x = cvt_pk_bf16(fmaf(xq_s, a0.x, c0.x), fmaf(xq_s, a0.y, c0.y));
            bfp.y = cvt_pk_bf16(fmaf(xq_s, a0.z, c0.z), fmaf(xq_s, a0.w, c0.w));
            bfp.z = cvt_pk_bf16(fmaf(xq_s, a1.x, c1.x), fmaf(xq_s, a1.y, c1.y));
            bfp.w = cvt_pk_bf16(fmaf(xq_s, a1.z, c1.z), fmaf(xq_s, a1.w, c1.w));
            const short8 bf = *(const short8*)&bfp;

            f32x4 acc = {0.f, 0.f, 0.f, 0.f};
            acc = __builtin_amdgcn_mfma_f32_16x16x32_bf16(af, bf, acc, 0, 0, 0);

            float sc[4];
            #pragma unroll
            for (int j = 0; j < 4; ++j) {
                const float vbj = __shfl(vbl, lg * 4 + j);
                sc[j] = acc[j] + tc_s + vbj;
                if (!((pm >> (lg * 4 + j)) & 1)) sc[j] = NEG_MIN;
            }
            float mx = fmaxf(fmaxf(sc[0], sc[1]), fmaxf(sc[2], sc[3]));
            mx = fmaxf(mx, __shfl_xor(mx, 16));
            mx = fmaxf(mx, __shfl_xor(mx, 32));
            float sum = 0.f;
            #pragma unroll
            for (int j = 0; j < 4; ++j) { sc[j] = __expf(sc[j] - mx); sum += sc[j]; }
            sum += __shfl_xor(sum, 16);
            sum += __shfl_xor(sum, 32);
            const float inv = 1.f / sum;

            if (r < R) {
                float4* op = (float4*)(out + ((size_t)(b0 + bb) * R + r) * L + lg * 4);
                *op = make_float4(sc[0] * inv, sc[1] * inv, sc[2] * inv, sc[3] * inv);
            }
        }
    }
}

extern "C" void kernel_launch(void* const* d_in, const int* in_sizes, int n_in,
                              void* d_out, int out_size, void* d_ws, size_t ws_size,
                              hipStream_t stream) {
    const float* rss   = (const float*)d_in[0];
    const float* feat  = (const float*)d_in[1];
    const float* pos   = (const float*)d_in[2];
    const float* prev  = (const float*)d_in[3];
    const int*   fmask = (const int*)d_in[4];
    const float* gw1   = (const float*)d_in[5];
    const float* gb1   = (const float*)d_in[6];
    const float* gw2   = (const float*)d_in[7];
    const float* gb2   = (const float*)d_in[8];
    const float* qw1   = (const float*)d_in[9];
    const float* qb1   = (const float*)d_in[10];
    const float* qw2   = (const float*)d_in[11];
    const float* qb2   = (const float*)d_in[12];
    const float* kw1   = (const float*)d_in[13];
    const float* kb1   = (const float*)d_in[14];
    const float* kw2   = (const float*)d_in[15];
    const float* kb2   = (const float*)d_in[16];
    const float* sigma = (const float*)d_in[17];
    float* out = (float*)d_out;
    float* ws  = (float*)d_ws;

    nfh_pre<<<1, 256, 0, stream>>>(qw1, qb1, qw2, qb2, kw2, kb2, kw1, kb1, fmask, ws);
    nfh_main<<<B_TOT / NB, 256, 0, stream>>>(
        rss, feat, pos, prev,
        gw1, gb1, gw2, gb2,
        sigma, ws, out);
}